// Round 1
// baseline (6890.250 us; speedup 1.0000x reference)
//
#include <hip/hip_runtime.h>
#include <hip/hip_bf16.h>

// Problem constants
constexpr int B_ = 32, S_ = 512, D_ = 512, H_ = 8, L_ = 4, F_ = 2048, DK_ = 64;
constexpr int M_ = B_ * S_;  // 16384 rows

typedef __attribute__((ext_vector_type(8))) short short8;
typedef __attribute__((ext_vector_type(4))) float f32x4;

__device__ inline unsigned short f2b(float f) {
  union { __hip_bfloat16 h; unsigned short u; } cv;
  cv.h = __float2bfloat16(f);
  return cv.u;
}
__device__ inline float b2f(unsigned short u) {
  union { unsigned int i; float f; } c;
  c.i = ((unsigned int)u) << 16;
  return c.f;
}
__device__ inline float waveReduceSum(float v) {
  #pragma unroll
  for (int o = 32; o > 0; o >>= 1) v += __shfl_xor(v, o);
  return v;
}
__device__ inline float waveReduceMax(float v) {
  #pragma unroll
  for (int o = 32; o > 0; o >>= 1) v = fmaxf(v, __shfl_xor(v, o));
  return v;
}

// ---------------- prep: x = q + pos (f32 + bf16), y = qa + pos (bf16) --------
__global__ void prep_kernel(const float4* __restrict__ q, const float4* __restrict__ qa,
                            const float4* __restrict__ pos, float4* __restrict__ xf,
                            uint2* __restrict__ xb, uint2* __restrict__ yb) {
  int i = blockIdx.x * blockDim.x + threadIdx.x;  // 2,097,152 exact
  float4 p = pos[i & 65535];                      // (S*D/4) = 65536
  float4 a = q[i], c = qa[i];
  float4 xv, yv;
  xv.x = a.x + p.x; xv.y = a.y + p.y; xv.z = a.z + p.z; xv.w = a.w + p.w;
  yv.x = c.x + p.x; yv.y = c.y + p.y; yv.z = c.z + p.z; yv.w = c.w + p.w;
  xf[i] = xv;
  uint2 px, py;
  px.x = (unsigned)f2b(xv.x) | ((unsigned)f2b(xv.y) << 16);
  px.y = (unsigned)f2b(xv.z) | ((unsigned)f2b(xv.w) << 16);
  py.x = (unsigned)f2b(yv.x) | ((unsigned)f2b(yv.y) << 16);
  py.y = (unsigned)f2b(yv.z) | ((unsigned)f2b(yv.w) << 16);
  xb[i] = px;
  yb[i] = py;
}

// ---------------- cast fp32 -> bf16 ------------------------------------------
__global__ void cast_kernel(const float4* __restrict__ src, uint2* __restrict__ dst, int n4) {
  int i = blockIdx.x * blockDim.x + threadIdx.x;
  if (i >= n4) return;
  float4 v = src[i];
  uint2 p;
  p.x = (unsigned)f2b(v.x) | ((unsigned)f2b(v.y) << 16);
  p.y = (unsigned)f2b(v.z) | ((unsigned)f2b(v.w) << 16);
  dst[i] = p;
}

// ---------------- bf16 MFMA GEMM: C[M,N] = A[M,K] @ W[N,K]^T + bias ----------
// 128x128 tile, BK=32, 4 waves (2x2 of 64x64), global_load_lds staging with
// XOR swizzle (chunk q ^= (R&7) within each 128B two-row region -> 2-way max
// bank aliasing on ds_read_b128, which is free).
template<int RELU, int STORE_BF16, int STORE_F32>
__global__ __launch_bounds__(256, 2) void gemm_bf16_kernel(
    const __hip_bfloat16* __restrict__ A,
    const __hip_bfloat16* __restrict__ W,
    const float* __restrict__ bias,
    float* __restrict__ Cf,
    __hip_bfloat16* __restrict__ Cb,
    int Ndim, int Kdim)
{
  __shared__ char lds[16384];  // A tile [0,8192), W tile [8192,16384)
  const int tid  = threadIdx.x;
  const int wave = tid >> 6;
  const int lane = tid & 63;
  const int wr = wave >> 1, wc = wave & 1;
  const int row0 = blockIdx.y * 128;
  const int col0 = blockIdx.x * 128;

  f32x4 acc[4][4] = {};

  // staging descriptors: wave covers two 1KB calls per tile
  int callbase[2], srow[2], sslot[2];
  #pragma unroll
  for (int c = 0; c < 2; ++c) {
    int p  = (wave * 2 + c) * 1024 + lane * 16;
    int R  = p >> 7;
    int q  = (p >> 4) & 7;
    int ql = q ^ (R & 7);
    srow[c]  = (R << 1) | (ql >> 2);
    sslot[c] = ql & 3;
    callbase[c] = (wave * 2 + c) * 1024;
  }

  // fragment read offsets (constant across K loop)
  int aoff[4], boff[4];
  {
    int s0 = lane >> 4, rl = lane & 15;
    #pragma unroll
    for (int m = 0; m < 4; ++m) {
      int r  = wr * 64 + m * 16 + rl;
      int R  = r >> 1;
      int q  = ((((r & 1) << 2) | s0) ^ (R & 7));
      aoff[m] = R * 128 + q * 16;
      int rc = wc * 64 + m * 16 + rl;
      int Rc = rc >> 1;
      int qc = ((((rc & 1) << 2) | s0) ^ (Rc & 7));
      boff[m] = 8192 + Rc * 128 + qc * 16;
    }
  }

  const size_t ldK = (size_t)Kdim;
  for (int k0 = 0; k0 < Kdim; k0 += 32) {
    #pragma unroll
    for (int c = 0; c < 2; ++c) {
      const __hip_bfloat16* ga = A + (size_t)(row0 + srow[c]) * ldK + (k0 + sslot[c] * 8);
      __builtin_amdgcn_global_load_lds(
          (const __attribute__((address_space(1))) void*)ga,
          (__attribute__((address_space(3))) void*)(lds + callbase[c]), 16, 0, 0);
      const __hip_bfloat16* gw = W + (size_t)(col0 + srow[c]) * ldK + (k0 + sslot[c] * 8);
      __builtin_amdgcn_global_load_lds(
          (const __attribute__((address_space(1))) void*)gw,
          (__attribute__((address_space(3))) void*)(lds + 8192 + callbase[c]), 16, 0, 0);
    }
    __syncthreads();
    short8 aF[4], bF[4];
    #pragma unroll
    for (int m = 0; m < 4; ++m) {
      aF[m] = *(const short8*)(lds + aoff[m]);
      bF[m] = *(const short8*)(lds + boff[m]);
    }
    #pragma unroll
    for (int m = 0; m < 4; ++m)
      #pragma unroll
      for (int n = 0; n < 4; ++n)
        acc[m][n] = __builtin_amdgcn_mfma_f32_16x16x32_bf16(aF[m], bF[n], acc[m][n], 0, 0, 0);
    __syncthreads();
  }

  // epilogue: C row = (lane>>4)*4+j, col = lane&15 within each 16x16 fragment
  const int cr = row0 + wr * 64 + (lane >> 4) * 4;
  const int cc = col0 + wc * 64 + (lane & 15);
  #pragma unroll
  for (int n = 0; n < 4; ++n) {
    int col = cc + n * 16;
    float bv = bias[col];
    #pragma unroll
    for (int m = 0; m < 4; ++m) {
      #pragma unroll
      for (int j = 0; j < 4; ++j) {
        int row = cr + m * 16 + j;
        float val = acc[m][n][j] + bv;
        if (RELU) val = fmaxf(val, 0.0f);
        size_t off = (size_t)row * Ndim + col;
        if (STORE_F32) Cf[off] = val;
        if (STORE_BF16) {
          union { __hip_bfloat16 h; unsigned short u; } cv;
          cv.u = f2b(val);
          Cb[off] = cv.h;
        }
      }
    }
  }
}

// ---------------- attention: per (b,h,s) block, strict-causal, fr-scaled -----
__global__ __launch_bounds__(256) void attn_kernel(
    const __hip_bfloat16* __restrict__ kq,  // [B*S, D] (head h at col h*64)
    const __hip_bfloat16* __restrict__ v,
    const float* __restrict__ fr,           // [B*S]
    __hip_bfloat16* __restrict__ ctx)       // [B*S, D]
{
  const int bid = blockIdx.x;
  const int s   = bid & (S_ - 1);
  const int bh  = bid >> 9;       // /S
  const int h   = bh & (H_ - 1);
  const int b   = bh >> 3;        // /H
  const int tid = threadIdx.x;
  const size_t headbase = ((size_t)b * S_) * D_ + (size_t)h * DK_;  // + t*D

  if (s == 0) {  // attn row 0 forced to zero -> ctx row 0 = 0
    if (tid < 32) ((unsigned int*)(ctx + headbase))[tid] = 0u;
    return;
  }

  __shared__ float qv[DK_];
  __shared__ float sc[S_];
  __shared__ float red[8];
  __shared__ float part[256];

  if (tid < DK_) qv[tid] = b2f((unsigned short)((const unsigned short*)kq)[headbase + (size_t)s * D_ + tid]);
  __syncthreads();

  const float sf = fr[b * S_ + s] * 0.125f;  // * 1/sqrt(64)

  // phase 1: scores for t < s
  for (int t = tid; t < s; t += 256) {
    const __hip_bfloat16* kr = kq + headbase + (size_t)t * D_;
    float a = 0.0f;
    #pragma unroll
    for (int kk = 0; kk < DK_; kk += 8) {
      short8 pk = *(const short8*)(kr + kk);
      #pragma unroll
      for (int j = 0; j < 8; ++j) a += qv[kk + j] * b2f((unsigned short)pk[j]);
    }
    sc[t] = a * sf;
  }
  __syncthreads();

  // phase 2: softmax over [0, s)
  const int lane = tid & 63, wv = tid >> 6;
  float lm = -3.0e38f;
  for (int t = tid; t < s; t += 256) lm = fmaxf(lm, sc[t]);
  lm = waveReduceMax(lm);
  if (lane == 0) red[wv] = lm;
  __syncthreads();
  float bmax = fmaxf(fmaxf(red[0], red[1]), fmaxf(red[2], red[3]));
  float ls = 0.0f;
  for (int t = tid; t < s; t += 256) {
    float e = __expf(sc[t] - bmax);
    sc[t] = e;
    ls += e;
  }
  ls = waveReduceSum(ls);
  if (lane == 0) red[4 + wv] = ls;
  __syncthreads();
  float inv = 1.0f / (red[4] + red[5] + red[6] + red[7]);

  // phase 3: ctx[dk] = inv * sum_t sc[t] * v[t][dk]
  const int dk = tid & 63, g = tid >> 6;
  float a = 0.0f;
  for (int t = g; t < s; t += 4)
    a += sc[t] * b2f((unsigned short)((const unsigned short*)v)[headbase + (size_t)t * D_ + dk]);
  part[tid] = a;
  __syncthreads();
  if (tid < 64) {
    float r = (part[tid] + part[tid + 64] + part[tid + 128] + part[tid + 192]) * inv;
    union { __hip_bfloat16 h; unsigned short u; } cv;
    cv.u = f2b(r);
    ctx[headbase + (size_t)s * D_ + tid] = cv.h;
  }
}

// ---------------- fused residual + LayerNorm (wave per row) ------------------
__global__ __launch_bounds__(256) void ln_kernel(
    const float4* __restrict__ xin, const float4* add,
    const float* __restrict__ g, const float* __restrict__ bta,
    float4* xf_out, uint2* __restrict__ xb_out)
{
  const int lane = threadIdx.x & 63, wv = threadIdx.x >> 6;
  const size_t row = (size_t)blockIdx.x * 4 + wv;
  const size_t base4 = row * 128;  // float4 index

  float4 x0 = xin[base4 + lane * 2], x1 = xin[base4 + lane * 2 + 1];
  float4 a0 = add[base4 + lane * 2], a1 = add[base4 + lane * 2 + 1];
  float v[8];
  v[0] = x0.x + a0.x; v[1] = x0.y + a0.y; v[2] = x0.z + a0.z; v[3] = x0.w + a0.w;
  v[4] = x1.x + a1.x; v[5] = x1.y + a1.y; v[6] = x1.z + a1.z; v[7] = x1.w + a1.w;
  float s = 0.0f;
  #pragma unroll
  for (int i = 0; i < 8; ++i) s += v[i];
  s = waveReduceSum(s);
  float mu = s * (1.0f / 512.0f);
  float vs = 0.0f;
  #pragma unroll
  for (int i = 0; i < 8; ++i) { float d = v[i] - mu; vs += d * d; }
  vs = waveReduceSum(vs);
  float rstd = rsqrtf(vs * (1.0f / 512.0f) + 1e-5f);

  const int c0 = lane * 8;
  float4 gg0 = *(const float4*)(g + c0), gg1 = *(const float4*)(g + c0 + 4);
  float4 bb0 = *(const float4*)(bta + c0), bb1 = *(const float4*)(bta + c0 + 4);
  float o[8];
  o[0] = (v[0] - mu) * rstd * gg0.x + bb0.x;
  o[1] = (v[1] - mu) * rstd * gg0.y + bb0.y;
  o[2] = (v[2] - mu) * rstd * gg0.z + bb0.z;
  o[3] = (v[3] - mu) * rstd * gg0.w + bb0.w;
  o[4] = (v[4] - mu) * rstd * gg1.x + bb1.x;
  o[5] = (v[5] - mu) * rstd * gg1.y + bb1.y;
  o[6] = (v[6] - mu) * rstd * gg1.z + bb1.z;
  o[7] = (v[7] - mu) * rstd * gg1.w + bb1.w;
  float4 w0, w1;
  w0.x = o[0]; w0.y = o[1]; w0.z = o[2]; w0.w = o[3];
  w1.x = o[4]; w1.y = o[5]; w1.z = o[6]; w1.w = o[7];
  xf_out[base4 + lane * 2] = w0;
  xf_out[base4 + lane * 2 + 1] = w1;
  uint2 p0, p1;
  p0.x = (unsigned)f2b(o[0]) | ((unsigned)f2b(o[1]) << 16);
  p0.y = (unsigned)f2b(o[2]) | ((unsigned)f2b(o[3]) << 16);
  p1.x = (unsigned)f2b(o[4]) | ((unsigned)f2b(o[5]) << 16);
  p1.y = (unsigned)f2b(o[6]) | ((unsigned)f2b(o[7]) << 16);
  xb_out[row * 128 + lane * 2] = p0;
  xb_out[row * 128 + lane * 2 + 1] = p1;
}

// ---------------- launcher ---------------------------------------------------
extern "C" void kernel_launch(void* const* d_in, const int* in_sizes, int n_in,
                              void* d_out, int out_size, void* d_ws, size_t ws_size,
                              hipStream_t stream) {
  (void)in_sizes; (void)n_in; (void)out_size; (void)ws_size;
  const float* q   = (const float*)d_in[0];
  const float* qa  = (const float*)d_in[1];
  const float* frr = (const float*)d_in[2];
  const float* pos = (const float*)d_in[3];
  const float* Wk  = (const float*)d_in[4];
  const float* bk  = (const float*)d_in[5];
  const float* Wv  = (const float*)d_in[6];
  const float* bv  = (const float*)d_in[7];
  const float* Wo  = (const float*)d_in[8];
  const float* bo  = (const float*)d_in[9];
  const float* W1  = (const float*)d_in[10];
  const float* b1  = (const float*)d_in[11];
  const float* W2  = (const float*)d_in[12];
  const float* b2  = (const float*)d_in[13];
  const float* g1  = (const float*)d_in[14];
  const float* be1 = (const float*)d_in[15];
  const float* g2  = (const float*)d_in[16];
  const float* be2 = (const float*)d_in[17];

  // workspace carve (total ~207.6 MB)
  char* ws = (char*)d_ws;
  float*          xf   = (float*)(ws + 0);                      // 33.5 MB
  __hip_bfloat16* xb   = (__hip_bfloat16*)(ws + 33554432);      // 16.8 MB
  __hip_bfloat16* yb   = (__hip_bfloat16*)(ws + 50331648);      // 16.8 MB
  __hip_bfloat16* kqb  = (__hip_bfloat16*)(ws + 67108864);      // 16.8 MB
  __hip_bfloat16* vb   = (__hip_bfloat16*)(ws + 83886080);      // 16.8 MB
  __hip_bfloat16* ctxb = (__hip_bfloat16*)(ws + 100663296);     // 16.8 MB
  __hip_bfloat16* hb   = (__hip_bfloat16*)(ws + 117440512);     // 67.1 MB
  __hip_bfloat16* wkb  = (__hip_bfloat16*)(ws + 184549376);
  __hip_bfloat16* wvb  = (__hip_bfloat16*)(ws + 186646528);
  __hip_bfloat16* wob  = (__hip_bfloat16*)(ws + 188743680);
  __hip_bfloat16* w1b  = (__hip_bfloat16*)(ws + 190840832);
  __hip_bfloat16* w2b  = (__hip_bfloat16*)(ws + 199229440);     // ends 207618048
  float* outf = (float*)d_out;  // reuse d_out as fp32 GEMM-out scratch

  prep_kernel<<<8192, 256, 0, stream>>>((const float4*)q, (const float4*)qa,
                                        (const float4*)pos, (float4*)xf,
                                        (uint2*)xb, (uint2*)yb);
  cast_kernel<<<1024, 256, 0, stream>>>((const float4*)Wk, (uint2*)wkb, 262144);
  cast_kernel<<<1024, 256, 0, stream>>>((const float4*)Wv, (uint2*)wvb, 262144);
  cast_kernel<<<1024, 256, 0, stream>>>((const float4*)Wo, (uint2*)wob, 262144);
  cast_kernel<<<4096, 256, 0, stream>>>((const float4*)W1, (uint2*)w1b, 1048576);
  cast_kernel<<<4096, 256, 0, stream>>>((const float4*)W2, (uint2*)w2b, 1048576);

  for (int l = 0; l < L_; ++l) {
    gemm_bf16_kernel<0,1,0><<<dim3(4, 128), 256, 0, stream>>>(
        xb, wkb + (size_t)l * 262144, bk + l * 512, nullptr, kqb, 512, 512);
    gemm_bf16_kernel<0,1,0><<<dim3(4, 128), 256, 0, stream>>>(
        yb, wvb + (size_t)l * 262144, bv + l * 512, nullptr, vb, 512, 512);
    attn_kernel<<<131072, 256, 0, stream>>>(kqb, vb, frr, ctxb);
    gemm_bf16_kernel<0,0,1><<<dim3(4, 128), 256, 0, stream>>>(
        ctxb, wob + (size_t)l * 262144, bo + l * 512, outf, nullptr, 512, 512);
    ln_kernel<<<4096, 256, 0, stream>>>((const float4*)xf, (const float4*)outf,
                                        g1 + l * 512, be1 + l * 512,
                                        (float4*)xf, (uint2*)xb);
    gemm_bf16_kernel<1,1,0><<<dim3(16, 128), 256, 0, stream>>>(
        xb, w1b + (size_t)l * 1048576, b1 + l * 2048, nullptr, hb, 2048, 512);
    gemm_bf16_kernel<0,0,1><<<dim3(4, 128), 256, 0, stream>>>(
        hb, w2b + (size_t)l * 1048576, b2 + l * 512, outf, nullptr, 512, 2048);
    float* lnout = (l == L_ - 1) ? (float*)d_out : xf;
    ln_kernel<<<4096, 256, 0, stream>>>((const float4*)xf, (const float4*)outf,
                                        g2 + l * 512, be2 + l * 512,
                                        (float4*)lnout, (uint2*)xb);
  }
}

// Round 2
// 1023.033 us; speedup vs baseline: 6.7351x; 6.7351x over previous
//
#include <hip/hip_runtime.h>
#include <hip/hip_bf16.h>

// Problem constants
constexpr int B_ = 32, S_ = 512, D_ = 512, H_ = 8, L_ = 4, F_ = 2048, DK_ = 64;

typedef __attribute__((ext_vector_type(8))) short short8;
typedef __attribute__((ext_vector_type(4))) float f32x4;

__device__ inline unsigned short f2b(float f) {
  union { __hip_bfloat16 h; unsigned short u; } cv;
  cv.h = __float2bfloat16(f);
  return cv.u;
}
__device__ inline float b2f(unsigned short u) {
  union { unsigned int i; float f; } c;
  c.i = ((unsigned int)u) << 16;
  return c.f;
}
__device__ inline float waveReduceSum(float v) {
  #pragma unroll
  for (int o = 32; o > 0; o >>= 1) v += __shfl_xor(v, o);
  return v;
}

// ---------------- prep: x = q + pos (f32 + bf16), y = qa + pos (bf16) --------
__global__ void prep_kernel(const float4* __restrict__ q, const float4* __restrict__ qa,
                            const float4* __restrict__ pos, float4* __restrict__ xf,
                            uint2* __restrict__ xb, uint2* __restrict__ yb) {
  int i = blockIdx.x * blockDim.x + threadIdx.x;  // 2,097,152 exact
  float4 p = pos[i & 65535];                      // (S*D/4) = 65536
  float4 a = q[i], c = qa[i];
  float4 xv, yv;
  xv.x = a.x + p.x; xv.y = a.y + p.y; xv.z = a.z + p.z; xv.w = a.w + p.w;
  yv.x = c.x + p.x; yv.y = c.y + p.y; yv.z = c.z + p.z; yv.w = c.w + p.w;
  xf[i] = xv;
  uint2 px, py;
  px.x = (unsigned)f2b(xv.x) | ((unsigned)f2b(xv.y) << 16);
  px.y = (unsigned)f2b(xv.z) | ((unsigned)f2b(xv.w) << 16);
  py.x = (unsigned)f2b(yv.x) | ((unsigned)f2b(yv.y) << 16);
  py.y = (unsigned)f2b(yv.z) | ((unsigned)f2b(yv.w) << 16);
  xb[i] = px;
  yb[i] = py;
}

// ---------------- cast fp32 -> bf16 ------------------------------------------
__global__ void cast_kernel(const float4* __restrict__ src, uint2* __restrict__ dst, int n4) {
  int i = blockIdx.x * blockDim.x + threadIdx.x;
  if (i >= n4) return;
  float4 v = src[i];
  uint2 p;
  p.x = (unsigned)f2b(v.x) | ((unsigned)f2b(v.y) << 16);
  p.y = (unsigned)f2b(v.z) | ((unsigned)f2b(v.w) << 16);
  dst[i] = p;
}

// ---------------- bf16 MFMA GEMM: C[M,N] = A[M,K] @ W[N,K]^T + bias ----------
// 128x128 tile, BK=32, 4 waves (2x2 of 64x64), global_load_lds staging with
// XOR swizzle. STORE_VT writes C transposed per head: vT[((b*8+h)*64+d)*512+t].
template<int RELU, int STORE_BF16, int STORE_F32, int STORE_VT>
__global__ __launch_bounds__(256, 2) void gemm_bf16_kernel(
    const __hip_bfloat16* __restrict__ A,
    const __hip_bfloat16* __restrict__ W,
    const float* __restrict__ bias,
    float* __restrict__ Cf,
    __hip_bfloat16* __restrict__ Cb,
    int Ndim, int Kdim)
{
  __shared__ char lds[16384];  // A tile [0,8192), W tile [8192,16384)
  const int tid  = threadIdx.x;
  const int wave = tid >> 6;
  const int lane = tid & 63;
  const int wr = wave >> 1, wc = wave & 1;
  const int row0 = blockIdx.y * 128;
  const int col0 = blockIdx.x * 128;

  f32x4 acc[4][4] = {};

  int callbase[2], srow[2], sslot[2];
  #pragma unroll
  for (int c = 0; c < 2; ++c) {
    int p  = (wave * 2 + c) * 1024 + lane * 16;
    int R  = p >> 7;
    int q  = (p >> 4) & 7;
    int ql = q ^ (R & 7);
    srow[c]  = (R << 1) | (ql >> 2);
    sslot[c] = ql & 3;
    callbase[c] = (wave * 2 + c) * 1024;
  }

  int aoff[4], boff[4];
  {
    int s0 = lane >> 4, rl = lane & 15;
    #pragma unroll
    for (int m = 0; m < 4; ++m) {
      int r  = wr * 64 + m * 16 + rl;
      int R  = r >> 1;
      int q  = ((((r & 1) << 2) | s0) ^ (R & 7));
      aoff[m] = R * 128 + q * 16;
      int rc = wc * 64 + m * 16 + rl;
      int Rc = rc >> 1;
      int qc = ((((rc & 1) << 2) | s0) ^ (Rc & 7));
      boff[m] = 8192 + Rc * 128 + qc * 16;
    }
  }

  const size_t ldK = (size_t)Kdim;
  for (int k0 = 0; k0 < Kdim; k0 += 32) {
    #pragma unroll
    for (int c = 0; c < 2; ++c) {
      const __hip_bfloat16* ga = A + (size_t)(row0 + srow[c]) * ldK + (k0 + sslot[c] * 8);
      __builtin_amdgcn_global_load_lds(
          (const __attribute__((address_space(1))) void*)ga,
          (__attribute__((address_space(3))) void*)(lds + callbase[c]), 16, 0, 0);
      const __hip_bfloat16* gw = W + (size_t)(col0 + srow[c]) * ldK + (k0 + sslot[c] * 8);
      __builtin_amdgcn_global_load_lds(
          (const __attribute__((address_space(1))) void*)gw,
          (__attribute__((address_space(3))) void*)(lds + 8192 + callbase[c]), 16, 0, 0);
    }
    __syncthreads();
    short8 aF[4], bF[4];
    #pragma unroll
    for (int m = 0; m < 4; ++m) {
      aF[m] = *(const short8*)(lds + aoff[m]);
      bF[m] = *(const short8*)(lds + boff[m]);
    }
    #pragma unroll
    for (int m = 0; m < 4; ++m)
      #pragma unroll
      for (int n = 0; n < 4; ++n)
        acc[m][n] = __builtin_amdgcn_mfma_f32_16x16x32_bf16(aF[m], bF[n], acc[m][n], 0, 0, 0);
    __syncthreads();
  }

  const int cr = row0 + wr * 64 + (lane >> 4) * 4;
  const int cc = col0 + wc * 64 + (lane & 15);
  #pragma unroll
  for (int n = 0; n < 4; ++n) {
    int col = cc + n * 16;
    float bv = bias[col];
    #pragma unroll
    for (int m = 0; m < 4; ++m) {
      #pragma unroll
      for (int j = 0; j < 4; ++j) {
        int row = cr + m * 16 + j;
        float val = acc[m][n][j] + bv;
        if (RELU) val = fmaxf(val, 0.0f);
        if (STORE_F32) Cf[(size_t)row * Ndim + col] = val;
        if (STORE_BF16) {
          union { __hip_bfloat16 h; unsigned short u; } cv;
          cv.u = f2b(val);
          Cb[(size_t)row * Ndim + col] = cv.h;
        }
        if (STORE_VT) {
          // vT[((b*8+h)*64+d)*512 + t], b=row>>9, t=row&511, h=col>>6, d=col&63
          size_t off = (((size_t)((row >> 9) * 8 + (col >> 6)) * 64 + (col & 63)) << 9) + (row & 511);
          union { __hip_bfloat16 h; unsigned short u; } cv;
          cv.u = f2b(val);
          Cb[off] = cv.h;
        }
      }
    }
  }
}

// ---------------- flash attention (MFMA, strict-causal, fr-scaled) -----------
// grid (S/128, B*H), 256 thr = 4 waves, wave owns 32 q-rows (2 x 16-row frags).
// K tiles of 64 staged in LDS (XOR swizzle), V pre-transposed (vT[bh][d][t]).
__global__ __launch_bounds__(256, 2) void fattn_kernel(
    const __hip_bfloat16* __restrict__ kq,  // [B*S, D]
    const __hip_bfloat16* __restrict__ vT,  // [(b*8+h)*64+d][t]  (S=512 per row)
    const float* __restrict__ fr,           // [B*S]
    __hip_bfloat16* __restrict__ ctx)       // [B*S, D]
{
  __shared__ char lds[24576];  // K [0,8K), Vt [8K,16K), P [16K + wave*2K)
  const int tid = threadIdx.x, wave = tid >> 6, lane = tid & 63;
  const int rl = lane & 15, gq = lane >> 4;
  const int qb = blockIdx.x * 128;
  const int bh = blockIdx.y;
  const int b = bh >> 3, h = bh & 7;
  const size_t kqbase = ((size_t)b * S_) * D_ + h * DK_;  // + q*512 elems
  const size_t vtbase = ((size_t)bh * DK_) * S_;          // + d*512 + t elems
  const int qw0 = qb + wave * 32;
  const int qw_end = qw0 + 32;

  // Q fragments in registers
  short8 qA[2][2];
  #pragma unroll
  for (int qf = 0; qf < 2; ++qf)
    #pragma unroll
    for (int kf = 0; kf < 2; ++kf)
      qA[qf][kf] = *(const short8*)(kq + kqbase + (size_t)(qw0 + qf * 16 + rl) * D_ + kf * 32 + gq * 8);

  // per-row forget scale
  float sfv[2][4];
  #pragma unroll
  for (int qf = 0; qf < 2; ++qf)
    #pragma unroll
    for (int j = 0; j < 4; ++j)
      sfv[qf][j] = fr[b * S_ + qw0 + qf * 16 + gq * 4 + j] * 0.125f;

  f32x4 o[2][4] = {};
  float mrow[2][4], lrow[2][4];
  #pragma unroll
  for (int qf = 0; qf < 2; ++qf)
    #pragma unroll
    for (int j = 0; j < 4; ++j) { mrow[qf][j] = -3.0e38f; lrow[qf][j] = 0.0f; }

  // staging descriptors (this wave's two 1KB segments)
  int sgoff[2], sldsoff[2];
  #pragma unroll
  for (int c = 0; c < 2; ++c) {
    int p = (wave * 2 + c) * 1024 + lane * 16;
    int r = p >> 7;
    int ch = (p >> 4) & 7;
    sgoff[c] = r * 1024 + ((ch ^ (r & 7)) << 4);
    sldsoff[c] = (wave * 2 + c) * 1024;
  }
  const char* kgbase = (const char*)kq + kqbase * 2;
  const char* vgbase = (const char*)vT + vtbase * 2;

  const int nt = (qb + 128) >> 6;
  for (int ti = 0; ti < nt; ++ti) {
    const int t0 = ti << 6;
    #pragma unroll
    for (int c = 0; c < 2; ++c) {
      __builtin_amdgcn_global_load_lds(
          (const __attribute__((address_space(1))) void*)(kgbase + (size_t)t0 * 1024 + sgoff[c]),
          (__attribute__((address_space(3))) void*)(lds + sldsoff[c]), 16, 0, 0);
      __builtin_amdgcn_global_load_lds(
          (const __attribute__((address_space(1))) void*)(vgbase + t0 * 2 + sgoff[c]),
          (__attribute__((address_space(3))) void*)(lds + 8192 + sldsoff[c]), 16, 0, 0);
    }
    __syncthreads();

    if (t0 < qw_end) {
      // K B-fragments: row = t, 16B at (kf*4+gq)-th chunk (swizzled)
      short8 kB[4][2];
      #pragma unroll
      for (int tf = 0; tf < 4; ++tf)
        #pragma unroll
        for (int kf = 0; kf < 2; ++kf) {
          int r = tf * 16 + rl;
          kB[tf][kf] = *(const short8*)(lds + r * 128 + (((kf * 4 + gq) ^ (r & 7)) << 4));
        }
      // V B-fragments: row = d
      short8 vB[4][2];
      #pragma unroll
      for (int df = 0; df < 4; ++df)
        #pragma unroll
        for (int kf = 0; kf < 2; ++kf) {
          int r = df * 16 + rl;
          vB[df][kf] = *(const short8*)(lds + 8192 + r * 128 + (((kf * 4 + gq) ^ (r & 7)) << 4));
        }

      #pragma unroll
      for (int qf = 0; qf < 2; ++qf) {
        f32x4 c4[4] = {};
        #pragma unroll
        for (int tf = 0; tf < 4; ++tf)
          #pragma unroll
          for (int kf = 0; kf < 2; ++kf)
            c4[tf] = __builtin_amdgcn_mfma_f32_16x16x32_bf16(qA[qf][kf], kB[tf][kf], c4[tf], 0, 0, 0);

        const int qg0 = qw0 + qf * 16 + gq * 4;
        // scale + strict-causal mask
        #pragma unroll
        for (int tf = 0; tf < 4; ++tf) {
          int tg = t0 + tf * 16 + rl;
          #pragma unroll
          for (int j = 0; j < 4; ++j) {
            float s = c4[tf][j] * sfv[qf][j];
            c4[tf][j] = (tg >= qg0 + j) ? -3.0e38f : s;
          }
        }
        // row max (per j): across tf, then across the 16-lane group
        float tm[4];
        #pragma unroll
        for (int j = 0; j < 4; ++j) {
          tm[j] = fmaxf(fmaxf(c4[0][j], c4[1][j]), fmaxf(c4[2][j], c4[3][j]));
          #pragma unroll
          for (int msk = 1; msk < 16; msk <<= 1) tm[j] = fmaxf(tm[j], __shfl_xor(tm[j], msk));
        }
        // online-softmax state update + O rescale
        #pragma unroll
        for (int j = 0; j < 4; ++j) {
          float mn = fmaxf(mrow[qf][j], tm[j]);
          float fac = __expf(mrow[qf][j] - mn);
          mrow[qf][j] = mn;
          lrow[qf][j] *= fac;
          #pragma unroll
          for (int df = 0; df < 4; ++df) o[qf][df][j] *= fac;
        }
        // exp, rowsum, write P to swizzled per-wave LDS
        float rs[4] = {0.f, 0.f, 0.f, 0.f};
        #pragma unroll
        for (int tf = 0; tf < 4; ++tf) {
          int tloc = tf * 16 + rl;
          #pragma unroll
          for (int j = 0; j < 4; ++j) {
            float e = __expf(c4[tf][j] - mrow[qf][j]);
            rs[j] += e;
            int qloc = gq * 4 + j;
            int addr = 16384 + wave * 2048 + qloc * 128 +
                       ((((tloc >> 3) ^ (qloc & 7)) << 4)) + (tloc & 7) * 2;
            *(unsigned short*)(lds + addr) = f2b(e);
          }
        }
        #pragma unroll
        for (int j = 0; j < 4; ++j) {
          float r = rs[j];
          #pragma unroll
          for (int msk = 1; msk < 16; msk <<= 1) r += __shfl_xor(r, msk);
          lrow[qf][j] += r;
        }
        // make P visible to the whole wave before A-frag reads
        asm volatile("s_waitcnt lgkmcnt(0)" ::: "memory");
        __builtin_amdgcn_sched_barrier(0);
        // PV
        short8 pA[2];
        #pragma unroll
        for (int kf = 0; kf < 2; ++kf)
          pA[kf] = *(const short8*)(lds + 16384 + wave * 2048 + rl * 128 +
                                    (((kf * 4 + gq) ^ (rl & 7)) << 4));
        #pragma unroll
        for (int df = 0; df < 4; ++df)
          #pragma unroll
          for (int kf = 0; kf < 2; ++kf)
            o[qf][df] = __builtin_amdgcn_mfma_f32_16x16x32_bf16(pA[kf], vB[df][kf], o[qf][df], 0, 0, 0);
      }
    }
    __syncthreads();
  }

  // epilogue
  #pragma unroll
  for (int qf = 0; qf < 2; ++qf)
    #pragma unroll
    for (int j = 0; j < 4; ++j) {
      int qg = qw0 + qf * 16 + gq * 4 + j;
      float inv = (qg == 0) ? 0.0f : 1.0f / lrow[qf][j];
      #pragma unroll
      for (int df = 0; df < 4; ++df) {
        union { __hip_bfloat16 hh; unsigned short u; } cv;
        cv.u = f2b(o[qf][df][j] * inv);
        ctx[((size_t)(b * S_ + qg)) * D_ + h * DK_ + df * 16 + rl] = cv.hh;
      }
    }
}

// ---------------- fused residual + LayerNorm (wave per row) ------------------
__global__ __launch_bounds__(256) void ln_kernel(
    const float4* __restrict__ xin, const float4* add,
    const float* __restrict__ g, const float* __restrict__ bta,
    float4* xf_out, uint2* __restrict__ xb_out)
{
  const int lane = threadIdx.x & 63, wv = threadIdx.x >> 6;
  const size_t row = (size_t)blockIdx.x * 4 + wv;
  const size_t base4 = row * 128;

  float4 x0 = xin[base4 + lane * 2], x1 = xin[base4 + lane * 2 + 1];
  float4 a0 = add[base4 + lane * 2], a1 = add[base4 + lane * 2 + 1];
  float v[8];
  v[0] = x0.x + a0.x; v[1] = x0.y + a0.y; v[2] = x0.z + a0.z; v[3] = x0.w + a0.w;
  v[4] = x1.x + a1.x; v[5] = x1.y + a1.y; v[6] = x1.z + a1.z; v[7] = x1.w + a1.w;
  float s = 0.0f;
  #pragma unroll
  for (int i = 0; i < 8; ++i) s += v[i];
  s = waveReduceSum(s);
  float mu = s * (1.0f / 512.0f);
  float vs = 0.0f;
  #pragma unroll
  for (int i = 0; i < 8; ++i) { float d = v[i] - mu; vs += d * d; }
  vs = waveReduceSum(vs);
  float rstd = rsqrtf(vs * (1.0f / 512.0f) + 1e-5f);

  const int c0 = lane * 8;
  float4 gg0 = *(const float4*)(g + c0), gg1 = *(const float4*)(g + c0 + 4);
  float4 bb0 = *(const float4*)(bta + c0), bb1 = *(const float4*)(bta + c0 + 4);
  float o[8];
  o[0] = (v[0] - mu) * rstd * gg0.x + bb0.x;
  o[1] = (v[1] - mu) * rstd * gg0.y + bb0.y;
  o[2] = (v[2] - mu) * rstd * gg0.z + bb0.z;
  o[3] = (v[3] - mu) * rstd * gg0.w + bb0.w;
  o[4] = (v[4] - mu) * rstd * gg1.x + bb1.x;
  o[5] = (v[5] - mu) * rstd * gg1.y + bb1.y;
  o[6] = (v[6] - mu) * rstd * gg1.z + bb1.z;
  o[7] = (v[7] - mu) * rstd * gg1.w + bb1.w;
  float4 w0, w1;
  w0.x = o[0]; w0.y = o[1]; w0.z = o[2]; w0.w = o[3];
  w1.x = o[4]; w1.y = o[5]; w1.z = o[6]; w1.w = o[7];
  xf_out[base4 + lane * 2] = w0;
  xf_out[base4 + lane * 2 + 1] = w1;
  uint2 p0, p1;
  p0.x = (unsigned)f2b(o[0]) | ((unsigned)f2b(o[1]) << 16);
  p0.y = (unsigned)f2b(o[2]) | ((unsigned)f2b(o[3]) << 16);
  p1.x = (unsigned)f2b(o[4]) | ((unsigned)f2b(o[5]) << 16);
  p1.y = (unsigned)f2b(o[6]) | ((unsigned)f2b(o[7]) << 16);
  xb_out[row * 128 + lane * 2] = p0;
  xb_out[row * 128 + lane * 2 + 1] = p1;
}

// ---------------- launcher ---------------------------------------------------
extern "C" void kernel_launch(void* const* d_in, const int* in_sizes, int n_in,
                              void* d_out, int out_size, void* d_ws, size_t ws_size,
                              hipStream_t stream) {
  (void)in_sizes; (void)n_in; (void)out_size; (void)ws_size;
  const float* q   = (const float*)d_in[0];
  const float* qa  = (const float*)d_in[1];
  const float* frr = (const float*)d_in[2];
  const float* pos = (const float*)d_in[3];
  const float* Wk  = (const float*)d_in[4];
  const float* bk  = (const float*)d_in[5];
  const float* Wv  = (const float*)d_in[6];
  const float* bv  = (const float*)d_in[7];
  const float* Wo  = (const float*)d_in[8];
  const float* bo  = (const float*)d_in[9];
  const float* W1  = (const float*)d_in[10];
  const float* b1  = (const float*)d_in[11];
  const float* W2  = (const float*)d_in[12];
  const float* b2  = (const float*)d_in[13];
  const float* g1  = (const float*)d_in[14];
  const float* be1 = (const float*)d_in[15];
  const float* g2  = (const float*)d_in[16];
  const float* be2 = (const float*)d_in[17];

  char* ws = (char*)d_ws;
  float*          xf   = (float*)(ws + 0);                      // 33.5 MB
  __hip_bfloat16* xb   = (__hip_bfloat16*)(ws + 33554432);
  __hip_bfloat16* yb   = (__hip_bfloat16*)(ws + 50331648);
  __hip_bfloat16* kqb  = (__hip_bfloat16*)(ws + 67108864);
  __hip_bfloat16* vtb  = (__hip_bfloat16*)(ws + 83886080);      // vT layout
  __hip_bfloat16* ctxb = (__hip_bfloat16*)(ws + 100663296);
  __hip_bfloat16* hb   = (__hip_bfloat16*)(ws + 117440512);
  __hip_bfloat16* wkb  = (__hip_bfloat16*)(ws + 184549376);
  __hip_bfloat16* wvb  = (__hip_bfloat16*)(ws + 186646528);
  __hip_bfloat16* wob  = (__hip_bfloat16*)(ws + 188743680);
  __hip_bfloat16* w1b  = (__hip_bfloat16*)(ws + 190840832);
  __hip_bfloat16* w2b  = (__hip_bfloat16*)(ws + 199229440);
  float* outf = (float*)d_out;

  prep_kernel<<<8192, 256, 0, stream>>>((const float4*)q, (const float4*)qa,
                                        (const float4*)pos, (float4*)xf,
                                        (uint2*)xb, (uint2*)yb);
  cast_kernel<<<1024, 256, 0, stream>>>((const float4*)Wk, (uint2*)wkb, 262144);
  cast_kernel<<<1024, 256, 0, stream>>>((const float4*)Wv, (uint2*)wvb, 262144);
  cast_kernel<<<1024, 256, 0, stream>>>((const float4*)Wo, (uint2*)wob, 262144);
  cast_kernel<<<4096, 256, 0, stream>>>((const float4*)W1, (uint2*)w1b, 1048576);
  cast_kernel<<<4096, 256, 0, stream>>>((const float4*)W2, (uint2*)w2b, 1048576);

  for (int l = 0; l < L_; ++l) {
    gemm_bf16_kernel<0,1,0,0><<<dim3(4, 128), 256, 0, stream>>>(
        xb, wkb + (size_t)l * 262144, bk + l * 512, nullptr, kqb, 512, 512);
    gemm_bf16_kernel<0,0,0,1><<<dim3(4, 128), 256, 0, stream>>>(
        yb, wvb + (size_t)l * 262144, bv + l * 512, nullptr, vtb, 512, 512);
    fattn_kernel<<<dim3(4, 256), 256, 0, stream>>>(kqb, vtb, frr, ctxb);
    gemm_bf16_kernel<0,0,1,0><<<dim3(4, 128), 256, 0, stream>>>(
        ctxb, wob + (size_t)l * 262144, bo + l * 512, outf, nullptr, 512, 512);
    ln_kernel<<<4096, 256, 0, stream>>>((const float4*)xf, (const float4*)outf,
                                        g1 + l * 512, be1 + l * 512,
                                        (float4*)xf, (uint2*)xb);
    gemm_bf16_kernel<1,1,0,0><<<dim3(16, 128), 256, 0, stream>>>(
        xb, w1b + (size_t)l * 1048576, b1 + l * 2048, nullptr, hb, 2048, 512);
    gemm_bf16_kernel<0,0,1,0><<<dim3(4, 128), 256, 0, stream>>>(
        hb, w2b + (size_t)l * 1048576, b2 + l * 512, outf, nullptr, 512, 2048);
    float* lnout = (l == L_ - 1) ? (float*)d_out : xf;
    ln_kernel<<<4096, 256, 0, stream>>>((const float4*)xf, (const float4*)outf,
                                        g2 + l * 512, be2 + l * 512,
                                        (float4*)lnout, (uint2*)xb);
  }
}